// Round 4
// baseline (96.246 us; speedup 1.0000x reference)
//
#include <hip/hip_runtime.h>

#define NBINS 128
#define NFREQ 64
#define HDIM 128
#define NQ 16384
#define EPSF 1e-8f

// d_ws layout:
//   [0, 128 KiB)         : packed probes float4 {pr, pi, -softplus(w), mw} at [f*NBINS + b]
//   [128 KiB, +12.58 MB) : Qpk — per query, 8 chunks of 24 floats {qr[8], qi[8], qm[8]}
#define QPK_OFF_BYTES (128 * 1024)
#define QPK_STRIDE 192               // floats per query
#define QPK_STRIDE4 48               // float4s per query
#define WS_NEEDED ((size_t)QPK_OFF_BYTES + (size_t)NQ * QPK_STRIDE * 4)

#define QN_BLOCKS (NQ / 64)                       // 256 blocks, 64 queries each
#define PACK_BLOCKS ((NBINS * NFREQ + 255) / 256) // 32 blocks

// ---------- Fused prologue: Q-normalize (blocks 0..255) + probe pack (rest) ----------
__global__ __launch_bounds__(256) void prologue_kernel(
    const float* __restrict__ Q,
    const float* __restrict__ probes,
    const float* __restrict__ wraw,
    const float* __restrict__ mw,
    float4* __restrict__ packed,
    float* __restrict__ Qpk) {
  const int blk = blockIdx.x;
  const int t = threadIdx.x;
  if (blk < QN_BLOCKS) {
    const int l = t & 3;                 // 4 lanes per query; lane l owns freqs [16l,16l+16)
    const int q = blk * 64 + (t >> 2);
    const float* qp = Q + (size_t)q * HDIM;
    float re[16], im[16];
    #pragma unroll
    for (int k = 0; k < 4; ++k) {
      *reinterpret_cast<float4*>(&re[k * 4]) =
          *reinterpret_cast<const float4*>(qp + 16 * l + k * 4);
      *reinterpret_cast<float4*>(&im[k * 4]) =
          *reinterpret_cast<const float4*>(qp + NFREQ + 16 * l + k * 4);
    }
    float s = 0.0f;
    #pragma unroll
    for (int k = 0; k < 16; ++k) {
      s = fmaf(re[k], re[k], s);
      s = fmaf(im[k], im[k], s);
    }
    s += __shfl_xor(s, 1, 4);
    s += __shfl_xor(s, 2, 4);
    const float inv = 1.0f / (__builtin_amdgcn_sqrtf(s) + EPSF);
    #pragma unroll
    for (int cc = 0; cc < 2; ++cc) {
      const int fc = 2 * l + cc;
      float qr[8], qi[8], qm[8];
      #pragma unroll
      for (int j = 0; j < 8; ++j) {
        const int k = cc * 8 + j;
        qr[j] = re[k] * inv;
        qi[j] = im[k] * inv;
        qm[j] = __builtin_amdgcn_sqrtf(fmaf(qr[j], qr[j], fmaf(qi[j], qi[j], EPSF)));
      }
      float* cp = Qpk + (size_t)q * QPK_STRIDE + fc * 24;
      *reinterpret_cast<float4*>(cp + 0)  = make_float4(qr[0], qr[1], qr[2], qr[3]);
      *reinterpret_cast<float4*>(cp + 4)  = make_float4(qr[4], qr[5], qr[6], qr[7]);
      *reinterpret_cast<float4*>(cp + 8)  = make_float4(qi[0], qi[1], qi[2], qi[3]);
      *reinterpret_cast<float4*>(cp + 12) = make_float4(qi[4], qi[5], qi[6], qi[7]);
      *reinterpret_cast<float4*>(cp + 16) = make_float4(qm[0], qm[1], qm[2], qm[3]);
      *reinterpret_cast<float4*>(cp + 20) = make_float4(qm[4], qm[5], qm[6], qm[7]);
    }
  } else {
    const int idx = (blk - QN_BLOCKS) * 256 + t;
    if (idx >= NBINS * NFREQ) return;
    const int b = idx >> 6;
    const int f = idx & 63;
    const float pr = probes[b * HDIM + f];
    const float pi = probes[b * HDIM + NFREQ + f];
    const float x = wraw[b * NFREQ + f];
    const float sp = fmaxf(x, 0.0f) + log1pf(expf(-fabsf(x)));  // stable softplus
    const float m = mw[b * NFREQ + f];
    packed[f * NBINS + b] = make_float4(pr, pi, -sp, m);
  }
}

// ---------- Main: q-broadcast via LDS (vector pipe), NOT scalar K$ misses ----------
__global__ __launch_bounds__(256, 6) void scorer4(
    const float* __restrict__ Qpk,
    const float4* __restrict__ packed,
    const float* __restrict__ bias,
    float* __restrict__ out) {
  __shared__ float4 qs4[8 * QPK_STRIDE4];  // 6 KB: 8 queries x 48 float4
  __shared__ float part[2][8][64];         // 2 KB: cross-wave f-combine
  const int t = threadIdx.x;
  const int qbase = blockIdx.x * 8;

  // Stage 8 queries' packed data into LDS (coalesced; LDS writes 2-way = free)
  {
    const float4* src =
        reinterpret_cast<const float4*>(Qpk + (size_t)qbase * QPK_STRIDE);
    qs4[t] = src[t];                        // 256 float4
    if (t < 128) qs4[256 + t] = src[256 + t];  // remaining 128
  }
  __syncthreads();

  const int lane = t & 63;
  const int wv = __builtin_amdgcn_readfirstlane(t >> 6);
  const int h = wv & 1;        // bin half
  const int fh = wv >> 1;      // freq half
  const int b = h * 64 + lane;

  float acc[8];
  #pragma unroll
  for (int q = 0; q < 8; ++q) acc[q] = 0.0f;

  for (int fci = 0; fci < 4; ++fci) {   // rolled: 4 chunks of 8 freqs in this half
    const int fc = fh * 4 + fci;
    float4 c[8];
    #pragma unroll
    for (int j = 0; j < 8; ++j)
      c[j] = packed[(fc * 8 + j) * NBINS + b];  // coalesced 1 KB, L1/L2-hot
    #pragma unroll
    for (int q = 0; q < 8; ++q) {
      const int qb = q * QPK_STRIDE4 + fc * 6;  // wave-uniform LDS base
      float4 r0 = qs4[qb + 0];   // ds_read_b128 broadcast, conflict-free
      float4 r1 = qs4[qb + 1];
      float4 i0 = qs4[qb + 2];
      float4 i1 = qs4[qb + 3];
      float4 m0 = qs4[qb + 4];
      float4 m1 = qs4[qb + 5];
      float qr[8] = {r0.x, r0.y, r0.z, r0.w, r1.x, r1.y, r1.z, r1.w};
      float qi[8] = {i0.x, i0.y, i0.z, i0.w, i1.x, i1.y, i1.z, i1.w};
      float qm[8] = {m0.x, m0.y, m0.z, m0.w, m1.x, m1.y, m1.z, m1.w};
      float a = acc[q];
      #pragma unroll
      for (int j = 0; j < 8; ++j) {
        float er = c[j].x - qr[j];
        float ei = c[j].y - qi[j];
        float d2 = fmaf(er, er, EPSF);
        d2 = fmaf(ei, ei, d2);
        float d = __builtin_amdgcn_sqrtf(d2);
        a = fmaf(d, c[j].z, a);
        a = fmaf(qm[j], c[j].w, a);
      }
      acc[q] = a;
    }
  }

  if (fh == 1) {
    #pragma unroll
    for (int q = 0; q < 8; ++q) part[h][q][lane] = acc[q];
  }
  __syncthreads();
  if (fh == 0) {
    const float bb = bias[b];
    #pragma unroll
    for (int q = 0; q < 8; ++q)
      out[(size_t)(qbase + q) * NBINS + b] = acc[q] + part[h][q][lane] + bb;
  }
}

// ---------- Fallback if ws too small (not expected; works from raw inputs) ----------
__global__ __launch_bounds__(256) void scorer_fallback(
    const float* __restrict__ Q,
    const float4* __restrict__ packed,
    const float* __restrict__ bias,
    float* __restrict__ out) {
  __shared__ float4 qlds[32][64];
  const int t = threadIdx.x;
  const int qbase = blockIdx.x * 32;
  {
    const int qi = t >> 3;
    const int f0 = (t & 7) * 8;
    const float* qp = Q + (size_t)(qbase + qi) * HDIM;
    float4 r0 = *reinterpret_cast<const float4*>(qp + f0);
    float4 r1 = *reinterpret_cast<const float4*>(qp + f0 + 4);
    float4 i0 = *reinterpret_cast<const float4*>(qp + NFREQ + f0);
    float4 i1 = *reinterpret_cast<const float4*>(qp + NFREQ + f0 + 4);
    float s = r0.x*r0.x + r0.y*r0.y + r0.z*r0.z + r0.w*r0.w
            + r1.x*r1.x + r1.y*r1.y + r1.z*r1.z + r1.w*r1.w
            + i0.x*i0.x + i0.y*i0.y + i0.z*i0.z + i0.w*i0.w
            + i1.x*i1.x + i1.y*i1.y + i1.z*i1.z + i1.w*i1.w;
    s += __shfl_xor(s, 1, 8);
    s += __shfl_xor(s, 2, 8);
    s += __shfl_xor(s, 4, 8);
    float inv = 1.0f / (__builtin_amdgcn_sqrtf(s) + EPSF);
    float re[8] = {r0.x, r0.y, r0.z, r0.w, r1.x, r1.y, r1.z, r1.w};
    float im[8] = {i0.x, i0.y, i0.z, i0.w, i1.x, i1.y, i1.z, i1.w};
    #pragma unroll
    for (int j = 0; j < 8; ++j) {
      float qr = re[j] * inv;
      float qim = im[j] * inv;
      float qm = __builtin_amdgcn_sqrtf(fmaf(qr, qr, fmaf(qim, qim, EPSF)));
      qlds[qi][f0 + j] = make_float4(qr, qim, qm, 0.0f);
    }
  }
  __syncthreads();
  const int w = t >> 6;
  const int lane = t & 63;
  const int b = (w & 1) * 64 + lane;
  const int qoff = (w >> 1) * 16;
  const float bb = bias[b];
  float acc[16];
  #pragma unroll
  for (int q = 0; q < 16; ++q) acc[q] = 0.0f;
  #pragma unroll
  for (int fc = 0; fc < 4; ++fc) {
    float4 c[16];
    #pragma unroll
    for (int fi = 0; fi < 16; ++fi)
      c[fi] = packed[(fc * 16 + fi) * NBINS + b];
    #pragma unroll 4
    for (int fi = 0; fi < 16; ++fi) {
      #pragma unroll
      for (int q = 0; q < 16; ++q) {
        float4 qv = qlds[qoff + q][fc * 16 + fi];
        float er = c[fi].x - qv.x;
        float ei = c[fi].y - qv.y;
        float d2 = fmaf(er, er, EPSF);
        d2 = fmaf(ei, ei, d2);
        float d = __builtin_amdgcn_sqrtf(d2);
        acc[q] = fmaf(d, c[fi].z, acc[q]);
        acc[q] = fmaf(qv.z, c[fi].w, acc[q]);
      }
    }
  }
  #pragma unroll
  for (int q = 0; q < 16; ++q)
    out[(size_t)(qbase + qoff + q) * NBINS + b] = acc[q] + bb;
}

extern "C" void kernel_launch(void* const* d_in, const int* in_sizes, int n_in,
                              void* d_out, int out_size, void* d_ws, size_t ws_size,
                              hipStream_t stream) {
  const float* Q      = (const float*)d_in[0];
  const float* probes = (const float*)d_in[1];
  const float* wraw   = (const float*)d_in[2];
  const float* mw     = (const float*)d_in[3];
  const float* bias   = (const float*)d_in[4];
  float* out = (float*)d_out;
  float4* packed = (float4*)d_ws;
  float* Qpk = (float*)((char*)d_ws + QPK_OFF_BYTES);

  prologue_kernel<<<QN_BLOCKS + PACK_BLOCKS, 256, 0, stream>>>(
      Q, probes, wraw, mw, packed, Qpk);
  if (ws_size >= WS_NEEDED) {
    scorer4<<<NQ / 8, 256, 0, stream>>>(Qpk, packed, bias, out);
  } else {
    scorer_fallback<<<NQ / 32, 256, 0, stream>>>(Q, packed, bias, out);
  }
}

// Round 5
// 45.474 us; speedup vs baseline: 2.1165x; 2.1165x over previous
//
#include <hip/hip_runtime.h>

#define NBINS 128
#define NFREQ 64
#define HDIM 128
#define NQ 16384
#define EPSF 1e-8f

// d_ws layout:
//   [0, 128 KiB)         : packed probes float4 {pr, pi, -softplus(w), mw} at [f*NBINS + b]
//   [128 KiB, +12.58 MB) : Qpk — per query, 8 chunks of 24 floats {qr[8], qi[8], qm[8]}
#define QPK_OFF_BYTES (128 * 1024)
#define QPK_STRIDE 192               // floats per query
#define QPK_STRIDE4 48               // float4s per query
#define WS_NEEDED ((size_t)QPK_OFF_BYTES + (size_t)NQ * QPK_STRIDE * 4)

#define QN_BLOCKS (NQ / 64)                       // 256 blocks, 64 queries each
#define PACK_BLOCKS ((NBINS * NFREQ + 255) / 256) // 32 blocks

// ---------- Fused prologue: Q-normalize (blocks 0..255) + probe pack (rest) ----------
__global__ __launch_bounds__(256) void prologue_kernel(
    const float* __restrict__ Q,
    const float* __restrict__ probes,
    const float* __restrict__ wraw,
    const float* __restrict__ mw,
    float4* __restrict__ packed,
    float* __restrict__ Qpk) {
  const int blk = blockIdx.x;
  const int t = threadIdx.x;
  if (blk < QN_BLOCKS) {
    const int l = t & 3;                 // 4 lanes per query; lane l owns freqs [16l,16l+16)
    const int q = blk * 64 + (t >> 2);
    const float* qp = Q + (size_t)q * HDIM;
    float re[16], im[16];
    #pragma unroll
    for (int k = 0; k < 4; ++k) {
      *reinterpret_cast<float4*>(&re[k * 4]) =
          *reinterpret_cast<const float4*>(qp + 16 * l + k * 4);
      *reinterpret_cast<float4*>(&im[k * 4]) =
          *reinterpret_cast<const float4*>(qp + NFREQ + 16 * l + k * 4);
    }
    float s = 0.0f;
    #pragma unroll
    for (int k = 0; k < 16; ++k) {
      s = fmaf(re[k], re[k], s);
      s = fmaf(im[k], im[k], s);
    }
    s += __shfl_xor(s, 1, 4);
    s += __shfl_xor(s, 2, 4);
    const float inv = 1.0f / (__builtin_amdgcn_sqrtf(s) + EPSF);
    #pragma unroll
    for (int cc = 0; cc < 2; ++cc) {
      const int fc = 2 * l + cc;
      float qr[8], qi[8], qm[8];
      #pragma unroll
      for (int j = 0; j < 8; ++j) {
        const int k = cc * 8 + j;
        qr[j] = re[k] * inv;
        qi[j] = im[k] * inv;
        qm[j] = __builtin_amdgcn_sqrtf(fmaf(qr[j], qr[j], fmaf(qi[j], qi[j], EPSF)));
      }
      float* cp = Qpk + (size_t)q * QPK_STRIDE + fc * 24;
      *reinterpret_cast<float4*>(cp + 0)  = make_float4(qr[0], qr[1], qr[2], qr[3]);
      *reinterpret_cast<float4*>(cp + 4)  = make_float4(qr[4], qr[5], qr[6], qr[7]);
      *reinterpret_cast<float4*>(cp + 8)  = make_float4(qi[0], qi[1], qi[2], qi[3]);
      *reinterpret_cast<float4*>(cp + 12) = make_float4(qi[4], qi[5], qi[6], qi[7]);
      *reinterpret_cast<float4*>(cp + 16) = make_float4(qm[0], qm[1], qm[2], qm[3]);
      *reinterpret_cast<float4*>(cp + 20) = make_float4(qm[4], qm[5], qm[6], qm[7]);
    }
  } else {
    const int idx = (blk - QN_BLOCKS) * 256 + t;
    if (idx >= NBINS * NFREQ) return;
    const int b = idx >> 6;
    const int f = idx & 63;
    const float pr = probes[b * HDIM + f];
    const float pi = probes[b * HDIM + NFREQ + f];
    const float x = wraw[b * NFREQ + f];
    const float sp = fmaxf(x, 0.0f) + log1pf(expf(-fabsf(x)));  // stable softplus
    const float m = mw[b * NFREQ + f];
    packed[f * NBINS + b] = make_float4(pr, pi, -sp, m);
  }
}

// ---------- Main: q-broadcast via LDS; default launch bounds so c[8] stays in VGPRs ----------
// (round-4 lesson: __launch_bounds__(256,6) -> 40 VGPR -> packed[] rematerialized in
//  inner loop -> 2.3x slower. Default bounds gave 68 VGPR in round 2 with this loop.)
__global__ __launch_bounds__(256) void scorer5(
    const float* __restrict__ Qpk,
    const float4* __restrict__ packed,
    const float* __restrict__ bias,
    float* __restrict__ out) {
  __shared__ float4 qs4[8 * QPK_STRIDE4];  // 6 KB: 8 queries x 48 float4
  __shared__ float part[2][8][64];         // 2 KB: cross-wave f-combine
  const int t = threadIdx.x;
  const int qbase = blockIdx.x * 8;

  // Stage 8 queries' packed data into LDS (coalesced float4; staged once per block)
  {
    const float4* src =
        reinterpret_cast<const float4*>(Qpk + (size_t)qbase * QPK_STRIDE);
    qs4[t] = src[t];
    if (t < 128) qs4[256 + t] = src[256 + t];
  }
  __syncthreads();

  const int lane = t & 63;
  const int wv = __builtin_amdgcn_readfirstlane(t >> 6);
  const int h = wv & 1;        // bin half
  const int fh = wv >> 1;      // freq half
  const int b = h * 64 + lane;

  float acc[8];
  #pragma unroll
  for (int q = 0; q < 8; ++q) acc[q] = 0.0f;

  for (int fci = 0; fci < 4; ++fci) {   // rolled: 4 chunks of 8 freqs in this half
    const int fc = fh * 4 + fci;
    float4 c[8];
    #pragma unroll
    for (int j = 0; j < 8; ++j)
      c[j] = packed[(fc * 8 + j) * NBINS + b];  // coalesced 1 KB, L1/L2-hot, hoisted
    #pragma unroll
    for (int q = 0; q < 8; ++q) {
      const int qb = q * QPK_STRIDE4 + fc * 6;  // wave-uniform LDS base
      float4 r0 = qs4[qb + 0];   // ds_read_b128 broadcast, conflict-free
      float4 r1 = qs4[qb + 1];
      float4 i0 = qs4[qb + 2];
      float4 i1 = qs4[qb + 3];
      float4 m0 = qs4[qb + 4];
      float4 m1 = qs4[qb + 5];
      float qr[8] = {r0.x, r0.y, r0.z, r0.w, r1.x, r1.y, r1.z, r1.w};
      float qi[8] = {i0.x, i0.y, i0.z, i0.w, i1.x, i1.y, i1.z, i1.w};
      float qm[8] = {m0.x, m0.y, m0.z, m0.w, m1.x, m1.y, m1.z, m1.w};
      float a = acc[q];
      #pragma unroll
      for (int j = 0; j < 8; ++j) {
        float er = c[j].x - qr[j];
        float ei = c[j].y - qi[j];
        float d2 = fmaf(er, er, EPSF);
        d2 = fmaf(ei, ei, d2);
        float d = __builtin_amdgcn_sqrtf(d2);
        a = fmaf(d, c[j].z, a);
        a = fmaf(qm[j], c[j].w, a);
      }
      acc[q] = a;
    }
  }

  if (fh == 1) {
    #pragma unroll
    for (int q = 0; q < 8; ++q) part[h][q][lane] = acc[q];
  }
  __syncthreads();
  if (fh == 0) {
    const float bb = bias[b];
    #pragma unroll
    for (int q = 0; q < 8; ++q)
      out[(size_t)(qbase + q) * NBINS + b] = acc[q] + part[h][q][lane] + bb;
  }
}

// ---------- Fallback if ws too small (not expected; works from raw inputs) ----------
__global__ __launch_bounds__(256) void scorer_fallback(
    const float* __restrict__ Q,
    const float4* __restrict__ packed,
    const float* __restrict__ bias,
    float* __restrict__ out) {
  __shared__ float4 qlds[32][64];
  const int t = threadIdx.x;
  const int qbase = blockIdx.x * 32;
  {
    const int qi = t >> 3;
    const int f0 = (t & 7) * 8;
    const float* qp = Q + (size_t)(qbase + qi) * HDIM;
    float4 r0 = *reinterpret_cast<const float4*>(qp + f0);
    float4 r1 = *reinterpret_cast<const float4*>(qp + f0 + 4);
    float4 i0 = *reinterpret_cast<const float4*>(qp + NFREQ + f0);
    float4 i1 = *reinterpret_cast<const float4*>(qp + NFREQ + f0 + 4);
    float s = r0.x*r0.x + r0.y*r0.y + r0.z*r0.z + r0.w*r0.w
            + r1.x*r1.x + r1.y*r1.y + r1.z*r1.z + r1.w*r1.w
            + i0.x*i0.x + i0.y*i0.y + i0.z*i0.z + i0.w*i0.w
            + i1.x*i1.x + i1.y*i1.y + i1.z*i1.z + i1.w*i1.w;
    s += __shfl_xor(s, 1, 8);
    s += __shfl_xor(s, 2, 8);
    s += __shfl_xor(s, 4, 8);
    float inv = 1.0f / (__builtin_amdgcn_sqrtf(s) + EPSF);
    float re[8] = {r0.x, r0.y, r0.z, r0.w, r1.x, r1.y, r1.z, r1.w};
    float im[8] = {i0.x, i0.y, i0.z, i0.w, i1.x, i1.y, i1.z, i1.w};
    #pragma unroll
    for (int j = 0; j < 8; ++j) {
      float qr = re[j] * inv;
      float qim = im[j] * inv;
      float qm = __builtin_amdgcn_sqrtf(fmaf(qr, qr, fmaf(qim, qim, EPSF)));
      qlds[qi][f0 + j] = make_float4(qr, qim, qm, 0.0f);
    }
  }
  __syncthreads();
  const int w = t >> 6;
  const int lane = t & 63;
  const int b = (w & 1) * 64 + lane;
  const int qoff = (w >> 1) * 16;
  const float bb = bias[b];
  float acc[16];
  #pragma unroll
  for (int q = 0; q < 16; ++q) acc[q] = 0.0f;
  #pragma unroll
  for (int fc = 0; fc < 4; ++fc) {
    float4 c[16];
    #pragma unroll
    for (int fi = 0; fi < 16; ++fi)
      c[fi] = packed[(fc * 16 + fi) * NBINS + b];
    #pragma unroll 4
    for (int fi = 0; fi < 16; ++fi) {
      #pragma unroll
      for (int q = 0; q < 16; ++q) {
        float4 qv = qlds[qoff + q][fc * 16 + fi];
        float er = c[fi].x - qv.x;
        float ei = c[fi].y - qv.y;
        float d2 = fmaf(er, er, EPSF);
        d2 = fmaf(ei, ei, d2);
        float d = __builtin_amdgcn_sqrtf(d2);
        acc[q] = fmaf(d, c[fi].z, acc[q]);
        acc[q] = fmaf(qv.z, c[fi].w, acc[q]);
      }
    }
  }
  #pragma unroll
  for (int q = 0; q < 16; ++q)
    out[(size_t)(qbase + qoff + q) * NBINS + b] = acc[q] + bb;
}

extern "C" void kernel_launch(void* const* d_in, const int* in_sizes, int n_in,
                              void* d_out, int out_size, void* d_ws, size_t ws_size,
                              hipStream_t stream) {
  const float* Q      = (const float*)d_in[0];
  const float* probes = (const float*)d_in[1];
  const float* wraw   = (const float*)d_in[2];
  const float* mw     = (const float*)d_in[3];
  const float* bias   = (const float*)d_in[4];
  float* out = (float*)d_out;
  float4* packed = (float4*)d_ws;
  float* Qpk = (float*)((char*)d_ws + QPK_OFF_BYTES);

  prologue_kernel<<<QN_BLOCKS + PACK_BLOCKS, 256, 0, stream>>>(
      Q, probes, wraw, mw, packed, Qpk);
  if (ws_size >= WS_NEEDED) {
    scorer5<<<NQ / 8, 256, 0, stream>>>(Qpk, packed, bias, out);
  } else {
    scorer_fallback<<<NQ / 32, 256, 0, stream>>>(Q, packed, bias, out);
  }
}